// Round 2
// baseline (4836.066 us; speedup 1.0000x reference)
//
#include <hip/hip_runtime.h>
#include <cstdint>
#include <cstddef>

// Problem constants
#define B_    16
#define S_    1024
#define DIM_  1024
#define H_    16
#define HD_   64
#define TDIM  3072   // 3*DIM

typedef unsigned short ushort;

// exact bf16 <-> f32 bit helpers
__device__ __forceinline__ float b2f(ushort u) {
    union { unsigned int i; float f; } t; t.i = (unsigned int)u << 16; return t.f;
}
__device__ __forceinline__ ushort f2b(float f) {
    union { float f; unsigned int i; } t; t.f = f;
    unsigned int r = t.i + 0x7FFFu + ((t.i >> 16) & 1u);   // RNE
    return (ushort)(r >> 16);
}

// ---------------------------------------------------------------------------
// Tiled GEMM  C[M,N] = A[M,K] @ B[K,N] + bias[N]
// AT: float or ushort(bf16 bits). CT: float or ushort(bf16 bits).
// 64x64 tile, 256 threads, 4x4 microtile, K-step 16. fp32 accumulation.
// ---------------------------------------------------------------------------
template<typename AT, typename CT>
__global__ __launch_bounds__(256) void gemm_tiled(const AT* __restrict__ A,
                                                  const float* __restrict__ Bm,
                                                  const float* __restrict__ bias,
                                                  CT* __restrict__ C,
                                                  int M, int N, int K) {
    __shared__ __align__(16) float As[16][68];   // [k][m]
    __shared__ __align__(16) float Bs[16][68];   // [k][n]

    const int tid = threadIdx.x;
    const int m0 = blockIdx.y * 64;
    const int n0 = blockIdx.x * 64;
    const int ty = tid >> 4;          // 0..15
    const int tx = tid & 15;          // 0..15

    const int ar = tid >> 2;          // A row 0..63
    const int ak = (tid & 3) * 4;     // 4 consecutive k
    const int bk = tid >> 4;          // B k-row 0..15
    const int bn = (tid & 15) * 4;    // 4 consecutive n

    const AT*    Aptr = A  + (size_t)(m0 + ar) * K + ak;
    const float* Bptr = Bm + (size_t)bk * N + n0 + bn;

    float acc[4][4] = {};

    for (int k0 = 0; k0 < K; k0 += 16) {
        float a0, a1, a2, a3;
        if constexpr (sizeof(AT) == 4) {
            float4 av = *(const float4*)(Aptr + k0);
            a0 = av.x; a1 = av.y; a2 = av.z; a3 = av.w;
        } else {
            ushort4 av = *(const ushort4*)(Aptr + k0);
            a0 = b2f(av.x); a1 = b2f(av.y); a2 = b2f(av.z); a3 = b2f(av.w);
        }
        float4 bv = *(const float4*)(Bptr + (size_t)k0 * N);
        As[ak + 0][ar] = a0;
        As[ak + 1][ar] = a1;
        As[ak + 2][ar] = a2;
        As[ak + 3][ar] = a3;
        *(float4*)&Bs[bk][bn] = bv;
        __syncthreads();
#pragma unroll
        for (int k = 0; k < 16; ++k) {
            float4 a = *(const float4*)&As[k][ty * 4];
            float4 b = *(const float4*)&Bs[k][tx * 4];
            acc[0][0] += a.x * b.x; acc[0][1] += a.x * b.y; acc[0][2] += a.x * b.z; acc[0][3] += a.x * b.w;
            acc[1][0] += a.y * b.x; acc[1][1] += a.y * b.y; acc[1][2] += a.y * b.z; acc[1][3] += a.y * b.w;
            acc[2][0] += a.z * b.x; acc[2][1] += a.z * b.y; acc[2][2] += a.z * b.z; acc[2][3] += a.z * b.w;
            acc[3][0] += a.w * b.x; acc[3][1] += a.w * b.y; acc[3][2] += a.w * b.z; acc[3][3] += a.w * b.w;
        }
        __syncthreads();
    }

#pragma unroll
    for (int i = 0; i < 4; ++i) {
        size_t row = (size_t)(m0 + ty * 4 + i) * N + n0 + tx * 4;
#pragma unroll
        for (int j = 0; j < 4; ++j) {
            float v = acc[i][j] + bias[n0 + tx * 4 + j];
            if constexpr (sizeof(CT) == 4) C[row + j] = v;
            else                           C[row + j] = f2b(v);
        }
    }
}

// ---------------------------------------------------------------------------
// Fused per-head RMSNorm + 2D-axial RoPE, in-place on bf16 qkv.
// One 64-lane wave per (b,s,h,{q|k}) row; lane d owns element d.
// RoPE angle computed inline:
//   d<32: pos=s>>5, i=d>>1 ; d>=32: pos=s&31, i=(d-32)>>1
//   angle = pos*0.5 * 10000^(-i/16)
// ---------------------------------------------------------------------------
__global__ __launch_bounds__(256) void rmsnorm_rope(ushort* __restrict__ qkv,
                                                    const float* __restrict__ qw,
                                                    const float* __restrict__ kw) {
    int wid  = blockIdx.x * 4 + (threadIdx.x >> 6);   // 0 .. 524287
    int lane = threadIdx.x & 63;
    int isK  = wid & 1;
    int row  = wid >> 1;          // (b*S + s)*H + h
    int h    = row & (H_ - 1);
    int bs   = row >> 4;          // b*S + s
    int s    = bs & (S_ - 1);

    ushort* p = qkv + (size_t)bs * TDIM + isK * DIM_ + h * HD_ + lane;
    float x = b2f(*p);

    float ss = x * x;
#pragma unroll
    for (int m = 32; m > 0; m >>= 1) ss += __shfl_xor(ss, m);
    float r = rsqrtf(ss * (1.0f / 64.0f) + 1e-6f);

    const float* w = isK ? kw : qw;
    float xn = x * r * w[lane];

    float part = __shfl_xor(xn, 32);
    float rot  = (lane < 32) ? -part : part;

    int pos = (lane < 32) ? (s >> 5) : (s & 31);
    int i   = (lane & 31) >> 1;
    // ln(10000)/16 = 0.5756462732485115
    float freq  = expf(-(float)i * 0.5756462732485115f);
    float angle = (float)pos * 0.5f * freq;
    float sn, c;
    __sincosf(angle, &sn, &c);

    *p = f2b(xn * c + rot * sn);
}

// ---------------------------------------------------------------------------
// Flash-style attention, fp32 compute, bf16 qkv input.
// Grid (S/64, B*H); block 256 thr.  Thread quad (4 lanes) owns one q-row:
//   r = tid>>2, q4 = tid&3; thread covers keys [q4*16,+16) for logits
//   and output dims [q4*16,+16) for PV.
// ---------------------------------------------------------------------------
template<typename OT>
__global__ __launch_bounds__(256) void attn_kernel(const ushort* __restrict__ qkv,
                                                   OT* __restrict__ out) {
    __shared__ __align__(16) float ks[64][68];
    __shared__ __align__(16) float vs[64][68];

    const int bh = blockIdx.y;
    const int b  = bh >> 4;
    const int h  = bh & 15;
    const int q0 = blockIdx.x * 64;

    const ushort* base = qkv + (size_t)b * S_ * TDIM + h * HD_;
    const ushort* qb = base;
    const ushort* kb = base + DIM_;
    const ushort* vb = base + 2 * DIM_;

    const int tid  = threadIdx.x;
    const int r    = tid >> 2;       // q-row within tile
    const int q4   = tid & 3;
    const int d0   = q4 * 16;
    const int lane = tid & 63;
    const int lbase = lane & ~3;

    // Q row -> registers (64 floats)
    float4 qv4[16];
    {
        const ushort* qrow = qb + (size_t)(q0 + r) * TDIM;
#pragma unroll
        for (int c4 = 0; c4 < 16; ++c4) {
            ushort4 u = *(const ushort4*)(qrow + c4 * 4);
            qv4[c4] = make_float4(b2f(u.x), b2f(u.y), b2f(u.z), b2f(u.w));
        }
    }

    float acc[16] = {};
    float mrun = -1e30f;
    float lrun = 0.0f;

    for (int kt = 0; kt < 16; ++kt) {
        __syncthreads();   // protect ks/vs from previous iteration's readers
#pragma unroll
        for (int i = 0; i < 4; ++i) {
            int e  = tid + i * 256;          // 0..1023
            int rr = e >> 4;
            int cq = (e & 15) * 4;
            size_t off = (size_t)(kt * 64 + rr) * TDIM + cq;
            ushort4 ku = *(const ushort4*)(kb + off);
            ushort4 vu = *(const ushort4*)(vb + off);
            *(float4*)&ks[rr][cq] = make_float4(b2f(ku.x), b2f(ku.y), b2f(ku.z), b2f(ku.w));
            *(float4*)&vs[rr][cq] = make_float4(b2f(vu.x), b2f(vu.y), b2f(vu.z), b2f(vu.w));
        }
        __syncthreads();

        // logits for my 16 keys
        float pl[16];
        float mx = -1e30f;
#pragma unroll
        for (int jj = 0; jj < 16; ++jj) {
            int j = d0 + jj;
            float dot = 0.0f;
#pragma unroll
            for (int c4 = 0; c4 < 16; ++c4) {
                float4 kv = *(const float4*)&ks[j][c4 * 4];
                dot += qv4[c4].x * kv.x + qv4[c4].y * kv.y +
                       qv4[c4].z * kv.z + qv4[c4].w * kv.w;
            }
            pl[jj] = dot * 0.125f;
            mx = fmaxf(mx, pl[jj]);
        }
        mx = fmaxf(mx, __shfl_xor(mx, 1));
        mx = fmaxf(mx, __shfl_xor(mx, 2));

        float mnew  = fmaxf(mrun, mx);
        float alpha = expf(mrun - mnew);

        float ssum = 0.0f;
#pragma unroll
        for (int jj = 0; jj < 16; ++jj) {
            pl[jj] = expf(pl[jj] - mnew);
            ssum += pl[jj];
        }
        ssum += __shfl_xor(ssum, 1);
        ssum += __shfl_xor(ssum, 2);

        lrun = lrun * alpha + ssum;
        mrun = mnew;

#pragma unroll
        for (int i = 0; i < 16; ++i) acc[i] *= alpha;

#pragma unroll
        for (int j = 0; j < 64; ++j) {
            float pv = __shfl(pl[j & 15], lbase | (j >> 4), 64);
            const float4* vrow = (const float4*)&vs[j][d0];
            float4 v0 = vrow[0], v1 = vrow[1], v2 = vrow[2], v3 = vrow[3];
            acc[0]  += pv * v0.x; acc[1]  += pv * v0.y; acc[2]  += pv * v0.z; acc[3]  += pv * v0.w;
            acc[4]  += pv * v1.x; acc[5]  += pv * v1.y; acc[6]  += pv * v1.z; acc[7]  += pv * v1.w;
            acc[8]  += pv * v2.x; acc[9]  += pv * v2.y; acc[10] += pv * v2.z; acc[11] += pv * v2.w;
            acc[12] += pv * v3.x; acc[13] += pv * v3.y; acc[14] += pv * v3.z; acc[15] += pv * v3.w;
        }
    }

    float inv = 1.0f / lrun;
    size_t orow = ((size_t)b * S_ + q0 + r) * DIM_ + h * HD_ + d0;
#pragma unroll
    for (int i = 0; i < 16; ++i) {
        float v = acc[i] * inv;
        if constexpr (sizeof(OT) == 4) out[orow + i] = v;
        else                           out[orow + i] = f2b(v);
    }
}

// ---------------------------------------------------------------------------
extern "C" void kernel_launch(void* const* d_in, const int* in_sizes, int n_in,
                              void* d_out, int out_size, void* d_ws, size_t ws_size,
                              hipStream_t stream) {
    const float* x        = (const float*)d_in[0];
    const float* w_qkv    = (const float*)d_in[1];
    const float* b_qkv    = (const float*)d_in[2];
    const float* q_norm_w = (const float*)d_in[3];
    const float* k_norm_w = (const float*)d_in[4];
    const float* w_out    = (const float*)d_in[5];
    const float* b_out    = (const float*)d_in[6];
    float* out = (float*)d_out;

    const size_t QKV_B = (size_t)16384 * 3072 * 2;   //  96 MiB (bf16)
    const size_t ATT_F = (size_t)16384 * 1024 * 4;   //  64 MiB (fp32)
    const size_t ATT_H = (size_t)16384 * 1024 * 2;   //  32 MiB (bf16)

    char* ws = (char*)d_ws;
    ushort* qkv = (ushort*)ws;

    if (ws_size >= QKV_B + ATT_F) {
        // Tier A: attn intermediate in fp32
        float* attn = (float*)(ws + QKV_B);

        gemm_tiled<float, ushort><<<dim3(48, 256), dim3(256), 0, stream>>>(
            x, w_qkv, b_qkv, qkv, 16384, 3072, 1024);
        rmsnorm_rope<<<dim3(131072), dim3(256), 0, stream>>>(qkv, q_norm_w, k_norm_w);
        attn_kernel<float><<<dim3(16, 256), dim3(256), 0, stream>>>(qkv, attn);
        gemm_tiled<float, float><<<dim3(16, 256), dim3(256), 0, stream>>>(
            attn, w_out, b_out, out, 16384, 1024, 1024);
    } else if (ws_size >= QKV_B + ATT_H) {
        // Tier B: attn intermediate in bf16
        ushort* attn = (ushort*)(ws + QKV_B);

        gemm_tiled<float, ushort><<<dim3(48, 256), dim3(256), 0, stream>>>(
            x, w_qkv, b_qkv, qkv, 16384, 3072, 1024);
        rmsnorm_rope<<<dim3(131072), dim3(256), 0, stream>>>(qkv, q_norm_w, k_norm_w);
        attn_kernel<ushort><<<dim3(16, 256), dim3(256), 0, stream>>>(qkv, attn);
        gemm_tiled<ushort, float><<<dim3(16, 256), dim3(256), 0, stream>>>(
            attn, w_out, b_out, out, 16384, 1024, 1024);
    } else {
        // Workspace too small for any plan: fail gracefully (diagnostic).
        hipMemsetAsync(d_out, 0, (size_t)out_size * sizeof(float), stream);
    }
}

// Round 3
// 438.963 us; speedup vs baseline: 11.0170x; 11.0170x over previous
//
#include <hip/hip_runtime.h>
#include <cstdint>
#include <cstddef>

#define B_    16
#define S_    1024
#define DIM_  1024
#define H_    16
#define HD_   64
#define TDIM  3072   // 3*DIM

typedef unsigned short ushort_t;
typedef unsigned int   uint_t;
typedef __attribute__((ext_vector_type(8))) short s8v;   // 8 bf16 bits = 4 VGPRs
typedef __attribute__((ext_vector_type(4))) float f32x4;

__device__ __forceinline__ float b2f(ushort_t u) {
    union { uint_t i; float f; } t; t.i = (uint_t)u << 16; return t.f;
}
__device__ __forceinline__ ushort_t f2b(float f) {
    union { float f; uint_t i; } t; t.f = f;
    uint_t r = t.i + 0x7FFFu + ((t.i >> 16) & 1u);   // RNE
    return (ushort_t)(r >> 16);
}

// MFMA via inline asm (HipKittens idiom): D[m][n] += sum_k A[m,k]*B[k,n]
// A-frag: lane&15 = m, (lane>>4)*8+j = k. B-frag: lane&15 = n, same k mapping.
// D-frag (HW-verified m89/m91): col = lane&15, row = (lane>>4)*4 + reg.
__device__ __forceinline__ f32x4 mfma_bf16(s8v a, s8v b, f32x4 c) {
    asm volatile("v_mfma_f32_16x16x32_bf16 %0, %1, %2, %0" : "+v"(c) : "v"(a), "v"(b));
    return c;
}

// ---------------------------------------------------------------------------
// fp32 -> bf16 elementwise (vectorized)
// ---------------------------------------------------------------------------
__global__ __launch_bounds__(256) void f32_to_bf16_vec(const float* __restrict__ src,
                                                       short* __restrict__ dst, int n4) {
    int i = blockIdx.x * 256 + threadIdx.x;
    if (i < n4) {
        float4 v = *(const float4*)(src + (size_t)i * 4);
        ushort4 o;
        o.x = f2b(v.x); o.y = f2b(v.y); o.z = f2b(v.z); o.w = f2b(v.w);
        *(ushort4*)(dst + (size_t)i * 4) = o;
    }
}

// ---------------------------------------------------------------------------
// W[K][N] fp32 -> WT[N][K] bf16  (32x32 LDS tile transpose)
// ---------------------------------------------------------------------------
__global__ __launch_bounds__(256) void transpose_to_bf16(const float* __restrict__ Wsrc,
                                                         short* __restrict__ WT,
                                                         int K, int N) {
    __shared__ float t[32][33];
    int tx = threadIdx.x & 31, ty = threadIdx.x >> 5;   // ty 0..7
    int n0 = blockIdx.x * 32, k0 = blockIdx.y * 32;
#pragma unroll
    for (int i = 0; i < 4; ++i)
        t[ty + 8 * i][tx] = Wsrc[(size_t)(k0 + ty + 8 * i) * N + n0 + tx];
    __syncthreads();
#pragma unroll
    for (int i = 0; i < 4; ++i)
        WT[(size_t)(n0 + ty + 8 * i) * K + k0 + tx] = (short)f2b(t[tx][ty + 8 * i]);
}

// ---------------------------------------------------------------------------
// bf16 MFMA GEMM: C[M,N] = A[M,K] @ B[K,N] + bias, with B given as BT[N,K].
// 128x128 tile, 4 waves, 4x4 fragments/wave, BK=32, reg-staged LDS (+8 pad).
// ---------------------------------------------------------------------------
template<typename CT>
__global__ __launch_bounds__(256) void gemm_bf16(const short* __restrict__ A,
                                                 const short* __restrict__ BT,
                                                 const float* __restrict__ bias,
                                                 CT* __restrict__ C,
                                                 int M, int N, int K) {
    __shared__ short As[128][40];
    __shared__ short Bs[128][40];

    const int tid  = threadIdx.x;
    const int w    = tid >> 6;
    const int lane = tid & 63;
    const int l15  = lane & 15, lg = lane >> 4;
    const int m0 = blockIdx.y * 128, n0 = blockIdx.x * 128;
    const int wr = (w >> 1) * 64, wc = (w & 1) * 64;

    const int r0 = tid >> 2;         // staging row 0..63 (and +64)
    const int p0 = (tid & 3) * 8;    // staging col {0,8,16,24}

    f32x4 acc[4][4] = {};

    for (int k0 = 0; k0 < K; k0 += 32) {
        __syncthreads();
        *(s8v*)&As[r0][p0]      = *(const s8v*)(A  + (size_t)(m0 + r0)      * K + k0 + p0);
        *(s8v*)&As[r0 + 64][p0] = *(const s8v*)(A  + (size_t)(m0 + r0 + 64) * K + k0 + p0);
        *(s8v*)&Bs[r0][p0]      = *(const s8v*)(BT + (size_t)(n0 + r0)      * K + k0 + p0);
        *(s8v*)&Bs[r0 + 64][p0] = *(const s8v*)(BT + (size_t)(n0 + r0 + 64) * K + k0 + p0);
        __syncthreads();

        s8v af[4], bf[4];
#pragma unroll
        for (int i = 0; i < 4; ++i) {
            af[i] = *(const s8v*)&As[wr + 16 * i + l15][lg * 8];
            bf[i] = *(const s8v*)&Bs[wc + 16 * i + l15][lg * 8];
        }
#pragma unroll
        for (int mi = 0; mi < 4; ++mi)
#pragma unroll
            for (int ni = 0; ni < 4; ++ni)
                acc[mi][ni] = mfma_bf16(af[mi], bf[ni], acc[mi][ni]);
    }

#pragma unroll
    for (int ni = 0; ni < 4; ++ni) {
        float bv = bias[n0 + wc + 16 * ni + l15];
#pragma unroll
        for (int mi = 0; mi < 4; ++mi) {
#pragma unroll
            for (int r = 0; r < 4; ++r) {
                size_t row = (size_t)(m0 + wr + 16 * mi + lg * 4 + r);
                int    col = n0 + wc + 16 * ni + l15;
                float v = acc[mi][ni][r] + bv;
                if constexpr (sizeof(CT) == 4) C[row * N + col] = v;
                else                           C[row * N + col] = (short)f2b(v);
            }
        }
    }
}

// ---------------------------------------------------------------------------
// Fused per-head RMSNorm + 2D-axial RoPE, in-place on bf16 qkv (unchanged).
// ---------------------------------------------------------------------------
__global__ __launch_bounds__(256) void rmsnorm_rope(ushort_t* __restrict__ qkv,
                                                    const float* __restrict__ qw,
                                                    const float* __restrict__ kw) {
    int wid  = blockIdx.x * 4 + (threadIdx.x >> 6);   // 0 .. 524287
    int lane = threadIdx.x & 63;
    int isK  = wid & 1;
    int row  = wid >> 1;
    int h    = row & (H_ - 1);
    int bs   = row >> 4;
    int s    = bs & (S_ - 1);

    ushort_t* p = qkv + (size_t)bs * TDIM + isK * DIM_ + h * HD_ + lane;
    float x = b2f(*p);

    float ss = x * x;
#pragma unroll
    for (int m = 32; m > 0; m >>= 1) ss += __shfl_xor(ss, m);
    float r = rsqrtf(ss * (1.0f / 64.0f) + 1e-6f);

    const float* w = isK ? kw : qw;
    float xn = x * r * w[lane];

    float part = __shfl_xor(xn, 32);
    float rot  = (lane < 32) ? -part : part;

    int pos = (lane < 32) ? (s >> 5) : (s & 31);
    int i   = (lane & 31) >> 1;
    float freq  = expf(-(float)i * 0.5756462732485115f);  // ln(10000)/16
    float angle = (float)pos * 0.5f * freq;
    float sn, c;
    __sincosf(angle, &sn, &c);

    *p = f2b(xn * c + rot * sn);
}

// ---------------------------------------------------------------------------
// MFMA flash attention. Grid (S/128, B*H), 256 thr = 4 waves.
// Wave w owns q rows [q0+32w, +32). Swapped QK^T: S^T = mfma(A=K, B=Q) so the
// softmax key-reduction is 16 in-lane values + shfl_xor(16,32).
// P goes through per-wave LDS (Ps) to re-layout for the PV A-operand.
// V staged transposed (Vt[d][key]) for the PV B-operand.
// ---------------------------------------------------------------------------
__global__ __launch_bounds__(256) void attn_mfma(const short* __restrict__ qkv,
                                                 short* __restrict__ attn) {
    __shared__ ushort_t Ks[64][72];        // K-tile  [key][d]
    __shared__ ushort_t Vt[64][72];        // V-tile^T [d][key]
    __shared__ ushort_t Ps[4][32][72];     // per-wave P [q_local][key]

    const int tid  = threadIdx.x;
    const int w    = tid >> 6;
    const int lane = tid & 63;
    const int l15  = lane & 15, lg = lane >> 4;
    const int bh = blockIdx.y, b = bh >> 4, h = bh & 15;
    const int q0 = blockIdx.x * 128;

    const short* qbase = qkv + (size_t)b * S_ * TDIM + h * HD_;

    // Q fragments (B-operand layout), held for the whole K/V loop
    s8v qf[2][2];
#pragma unroll
    for (int mq = 0; mq < 2; ++mq)
#pragma unroll
        for (int kk = 0; kk < 2; ++kk)
            qf[mq][kk] = *(const s8v*)(qbase + (size_t)(q0 + w * 32 + mq * 16 + l15) * TDIM
                                       + kk * 32 + lg * 8);

    f32x4 of[2][4] = {};
    float m_s[2] = {-1e30f, -1e30f};
    float l_s[2] = {0.f, 0.f};

    const int kr  = tid >> 3;          // K staging row (and +32)
    const int kp8 = (tid & 7) * 8;     // K staging col
    const int vkp = tid >> 3;          // V key-pair 0..31
    const int vp8 = (tid & 7) * 8;     // V d-base

    for (int kt = 0; kt < 16; ++kt) {
        __syncthreads();   // previous tile fully consumed
        {
            const short* kb = qkv + ((size_t)b * S_ + kt * 64) * TDIM + DIM_ + h * HD_;
            *(s8v*)&Ks[kr][kp8]      = *(const s8v*)(kb + (size_t)kr * TDIM + kp8);
            *(s8v*)&Ks[kr + 32][kp8] = *(const s8v*)(kb + (size_t)(kr + 32) * TDIM + kp8);
            const short* vb = qkv + ((size_t)b * S_ + kt * 64) * TDIM + 2 * DIM_ + h * HD_;
            s8v v0 = *(const s8v*)(vb + (size_t)(2 * vkp)     * TDIM + vp8);
            s8v v1 = *(const s8v*)(vb + (size_t)(2 * vkp + 1) * TDIM + vp8);
#pragma unroll
            for (int j = 0; j < 8; ++j) {
                uint_t pk = (ushort_t)v0[j] | ((uint_t)(ushort_t)v1[j] << 16);
                *(uint_t*)&Vt[vp8 + j][2 * vkp] = pk;
            }
        }
        __syncthreads();

        // ---- QK^T (swapped): st[nk][mq] holds S^T[key][q] fragments
        f32x4 st[4][2] = {};
#pragma unroll
        for (int kk = 0; kk < 2; ++kk) {
            s8v kf[4];
#pragma unroll
            for (int nk = 0; nk < 4; ++nk)
                kf[nk] = *(const s8v*)&Ks[nk * 16 + l15][kk * 32 + lg * 8];
#pragma unroll
            for (int nk = 0; nk < 4; ++nk)
#pragma unroll
                for (int mq = 0; mq < 2; ++mq)
                    st[nk][mq] = mfma_bf16(kf[nk], qf[mq][kk], st[nk][mq]);
        }

        // ---- online softmax per q-column (q = 16*mq + l15)
#pragma unroll
        for (int mq = 0; mq < 2; ++mq) {
            float mx = -1e30f;
#pragma unroll
            for (int nk = 0; nk < 4; ++nk)
#pragma unroll
                for (int r = 0; r < 4; ++r) {
                    st[nk][mq][r] *= 0.125f;           // 1/sqrt(HD)
                    mx = fmaxf(mx, st[nk][mq][r]);
                }
            mx = fmaxf(mx, __shfl_xor(mx, 16));
            mx = fmaxf(mx, __shfl_xor(mx, 32));
            float mnew  = fmaxf(m_s[mq], mx);
            float alpha = __expf(m_s[mq] - mnew);
            m_s[mq] = mnew;

            float ls = 0.f;
#pragma unroll
            for (int nk = 0; nk < 4; ++nk) {
#pragma unroll
                for (int r = 0; r < 4; ++r) {
                    float p = __expf(st[nk][mq][r] - mnew);
                    st[nk][mq][r] = p;
                    ls += p;
                }
            }
            ls += __shfl_xor(ls, 16);
            ls += __shfl_xor(ls, 32);
            l_s[mq] = l_s[mq] * alpha + ls;

            // P -> bf16 -> per-wave LDS (keys 16nk + lg*4 .. +4 are contiguous)
#pragma unroll
            for (int nk = 0; nk < 4; ++nk) {
                ushort4 pk;
                pk.x = f2b(st[nk][mq][0]); pk.y = f2b(st[nk][mq][1]);
                pk.z = f2b(st[nk][mq][2]); pk.w = f2b(st[nk][mq][3]);
                *(ushort4*)&Ps[w][mq * 16 + l15][nk * 16 + lg * 4] = pk;
            }

            // rescale O accumulator (alpha is per-q; move to row layout)
            float a4[4];
#pragma unroll
            for (int r = 0; r < 4; ++r) a4[r] = __shfl(alpha, lg * 4 + r);
#pragma unroll
            for (int nd = 0; nd < 4; ++nd)
#pragma unroll
                for (int r = 0; r < 4; ++r) of[mq][nd][r] *= a4[r];
        }

        // ---- PV: O[q][d] += P[q][key] * V[key][d]
#pragma unroll
        for (int kk = 0; kk < 2; ++kk) {
            s8v pf[2], vf[4];
#pragma unroll
            for (int mq = 0; mq < 2; ++mq)
                pf[mq] = *(const s8v*)&Ps[w][mq * 16 + l15][kk * 32 + lg * 8];
#pragma unroll
            for (int nd = 0; nd < 4; ++nd)
                vf[nd] = *(const s8v*)&Vt[nd * 16 + l15][kk * 32 + lg * 8];
#pragma unroll
            for (int mq = 0; mq < 2; ++mq)
#pragma unroll
                for (int nd = 0; nd < 4; ++nd)
                    of[mq][nd] = mfma_bf16(pf[mq], vf[nd], of[mq][nd]);
        }
    }

    // epilogue: divide by softmax sum, write bf16
#pragma unroll
    for (int mq = 0; mq < 2; ++mq) {
        float rinv = 1.0f / l_s[mq];
        float iv[4];
#pragma unroll
        for (int r = 0; r < 4; ++r) iv[r] = __shfl(rinv, lg * 4 + r);
#pragma unroll
        for (int nd = 0; nd < 4; ++nd)
#pragma unroll
            for (int r = 0; r < 4; ++r) {
                int row = q0 + w * 32 + mq * 16 + lg * 4 + r;
                attn[((size_t)b * S_ + row) * DIM_ + h * HD_ + nd * 16 + l15] =
                    (short)f2b(of[mq][nd][r] * iv[r]);
            }
    }
}

// ---------------------------------------------------------------------------
extern "C" void kernel_launch(void* const* d_in, const int* in_sizes, int n_in,
                              void* d_out, int out_size, void* d_ws, size_t ws_size,
                              hipStream_t stream) {
    const float* x        = (const float*)d_in[0];
    const float* w_qkv    = (const float*)d_in[1];
    const float* b_qkv    = (const float*)d_in[2];
    const float* q_norm_w = (const float*)d_in[3];
    const float* k_norm_w = (const float*)d_in[4];
    const float* w_out    = (const float*)d_in[5];
    const float* b_out    = (const float*)d_in[6];
    float* out = (float*)d_out;

    // workspace layout (136 MiB total)
    const size_t OFF_QKV = 0;                       //  96 MiB: qkv bf16 [16384][3072]
    const size_t OFF_XB  = 100663296;               //  32 MiB: xb bf16 / attn bf16 (aliased)
    const size_t OFF_WQ  = OFF_XB + 33554432;       //   6 MiB: w_qkv^T bf16 [3072][1024]
    const size_t OFF_WO  = OFF_WQ + 6291456;        //   2 MiB: w_out^T bf16 [1024][1024]
    const size_t NEED    = OFF_WO + 2097152;

    if (ws_size < NEED) {
        hipMemsetAsync(d_out, 0, (size_t)out_size * sizeof(float), stream);
        return;
    }

    char* ws = (char*)d_ws;
    short* qkv   = (short*)(ws + OFF_QKV);
    short* xb    = (short*)(ws + OFF_XB);      // also reused as attn output
    short* wqkvT = (short*)(ws + OFF_WQ);
    short* woutT = (short*)(ws + OFF_WO);

    // 1: convert inputs to bf16 (weights transposed to [N][K])
    f32_to_bf16_vec<<<dim3(16384), dim3(256), 0, stream>>>(x, xb, 4194304);
    transpose_to_bf16<<<dim3(96, 32), dim3(256), 0, stream>>>(w_qkv, wqkvT, 1024, 3072);
    transpose_to_bf16<<<dim3(32, 32), dim3(256), 0, stream>>>(w_out, woutT, 1024, 1024);

    // 2: qkv = x @ w_qkv + b_qkv   (MFMA, bf16 out)
    gemm_bf16<short><<<dim3(24, 128), dim3(256), 0, stream>>>(
        xb, wqkvT, b_qkv, qkv, 16384, 3072, 1024);

    // 3: per-head RMSNorm + RoPE on q,k (in place)
    rmsnorm_rope<<<dim3(131072), dim3(256), 0, stream>>>(
        (ushort_t*)qkv, q_norm_w, k_norm_w);

    // 4: flash attention -> attn (bf16), reusing xb buffer
    attn_mfma<<<dim3(8, 256), dim3(256), 0, stream>>>(qkv, xb);

    // 5: out = attn @ w_out + b_out  (MFMA, fp32 out)
    gemm_bf16<float><<<dim3(8, 128), dim3(256), 0, stream>>>(
        xb, woutT, b_out, out, 16384, 1024, 1024);
}

// Round 4
// 423.435 us; speedup vs baseline: 11.4210x; 1.0367x over previous
//
#include <hip/hip_runtime.h>
#include <cstdint>
#include <cstddef>

#define B_    16
#define S_    1024
#define DIM_  1024
#define H_    16
#define HD_   64
#define TDIM  3072   // 3*DIM

typedef unsigned short ushort_t;
typedef unsigned int   uint_t;
typedef __attribute__((ext_vector_type(8))) short s8v;   // 8 bf16 = 4 VGPRs
typedef __attribute__((ext_vector_type(4))) float f32x4;

__device__ __forceinline__ float b2f(ushort_t u) {
    union { uint_t i; float f; } t; t.i = (uint_t)u << 16; return t.f;
}
__device__ __forceinline__ ushort_t f2b(float f) {
    union { float f; uint_t i; } t; t.f = f;
    uint_t r = t.i + 0x7FFFu + ((t.i >> 16) & 1u);   // RNE
    return (ushort_t)(r >> 16);
}

// D[m][n] += sum_k A[m,k]*B[k,n].
// A-frag: lane&15=m, (lane>>4)*8+j=k. B-frag: lane&15=n, same k.
// D-frag (HW-verified m89/m91): col=lane&15, row=(lane>>4)*4+reg.
__device__ __forceinline__ f32x4 mfma_bf16(s8v a, s8v b, f32x4 c) {
    asm volatile("v_mfma_f32_16x16x32_bf16 %0, %1, %2, %0" : "+v"(c) : "v"(a), "v"(b));
    return c;
}

// ---------------------------------------------------------------------------
// RoPE cos/sin tables [S][HD] fp32 (512 KB, L2/L3-resident).
//   d<32: pos=s>>5, i=d>>1 ; d>=32: pos=s&31, i=(d-32)>>1
//   angle = pos*0.5 * 10000^(-i/16)
// ---------------------------------------------------------------------------
__global__ __launch_bounds__(256) void rope_tables(float* __restrict__ cos_t,
                                                   float* __restrict__ sin_t) {
    int idx = blockIdx.x * 256 + threadIdx.x;     // 0 .. 65535
    int s = idx >> 6;
    int d = idx & 63;
    int pos = (d < 32) ? (s >> 5) : (s & 31);
    int i   = (d & 31) >> 1;
    float freq  = expf(-(float)i * 0.5756462732485115f);   // ln(10000)/16
    float angle = (float)pos * 0.5f * freq;
    cos_t[idx] = cosf(angle);
    sin_t[idx] = sinf(angle);
}

// ---------------------------------------------------------------------------
// W[K][N] fp32 -> WT[N][K] bf16  (32x32 LDS tile transpose)
// ---------------------------------------------------------------------------
__global__ __launch_bounds__(256) void transpose_to_bf16(const float* __restrict__ Wsrc,
                                                         short* __restrict__ WT,
                                                         int K, int N) {
    __shared__ float t[32][33];
    int tx = threadIdx.x & 31, ty = threadIdx.x >> 5;   // ty 0..7
    int n0 = blockIdx.x * 32, k0 = blockIdx.y * 32;
#pragma unroll
    for (int i = 0; i < 4; ++i)
        t[ty + 8 * i][tx] = Wsrc[(size_t)(k0 + ty + 8 * i) * N + n0 + tx];
    __syncthreads();
#pragma unroll
    for (int i = 0; i < 4; ++i)
        WT[(size_t)(n0 + ty + 8 * i) * K + k0 + tx] = (short)f2b(t[tx][ty + 8 * i]);
}

// ---------------------------------------------------------------------------
// bf16 MFMA GEMM with reg-prefetch double buffering.
//   C[M,N] = A[M,K] @ B[K,N] + bias, B given as BT[N,K].
//   AF32: A is fp32, converted to bf16 during staging.
//   NORM: fused per-head RMSNorm + RoPE epilogue for columns < 2048 (q,k).
// 128x128 tile, 4 waves, 4x4 fragments/wave, BK=32.
// ---------------------------------------------------------------------------
template<typename CT, bool AF32, bool NORM>
__global__ __launch_bounds__(256) void gemm_bf16(
        const void* __restrict__ Avoid, const short* __restrict__ BT,
        const float* __restrict__ bias, CT* __restrict__ C,
        int M, int N, int K,
        const float* __restrict__ qw, const float* __restrict__ kw,
        const float* __restrict__ cos_t, const float* __restrict__ sin_t) {
    __shared__ short As[128][40];
    __shared__ short Bs[128][40];

    const float* Af = (const float*)Avoid;
    const short* Ab = (const short*)Avoid;

    const int tid  = threadIdx.x;
    const int w    = tid >> 6;
    const int lane = tid & 63;
    const int l15  = lane & 15, lg = lane >> 4;
    const int m0 = blockIdx.y * 128, n0 = blockIdx.x * 128;
    const int wr = (w >> 1) * 64, wc = (w & 1) * 64;

    const int r0 = tid >> 2;         // staging row 0..63 (and +64)
    const int p0 = (tid & 3) * 8;    // staging col {0,8,16,24}

    // prefetch registers
    float4 pa[2][2];   // AF32 path
    s8v    pab[2];     // bf16 path
    s8v    pb[2];

    auto prefetch = [&](int k0) {
        if constexpr (AF32) {
            const float* a0 = Af + (size_t)(m0 + r0) * K + k0 + p0;
            const float* a1 = Af + (size_t)(m0 + r0 + 64) * K + k0 + p0;
            pa[0][0] = *(const float4*)(a0);
            pa[0][1] = *(const float4*)(a0 + 4);
            pa[1][0] = *(const float4*)(a1);
            pa[1][1] = *(const float4*)(a1 + 4);
        } else {
            pab[0] = *(const s8v*)(Ab + (size_t)(m0 + r0) * K + k0 + p0);
            pab[1] = *(const s8v*)(Ab + (size_t)(m0 + r0 + 64) * K + k0 + p0);
        }
        pb[0] = *(const s8v*)(BT + (size_t)(n0 + r0) * K + k0 + p0);
        pb[1] = *(const s8v*)(BT + (size_t)(n0 + r0 + 64) * K + k0 + p0);
    };

    prefetch(0);

    f32x4 acc[4][4] = {};

    for (int k0 = 0; k0 < K; k0 += 32) {
        // write prefetched tile -> LDS
        if constexpr (AF32) {
#pragma unroll
            for (int hh = 0; hh < 2; ++hh) {
                s8v t;
                t[0] = (short)f2b(pa[hh][0].x); t[1] = (short)f2b(pa[hh][0].y);
                t[2] = (short)f2b(pa[hh][0].z); t[3] = (short)f2b(pa[hh][0].w);
                t[4] = (short)f2b(pa[hh][1].x); t[5] = (short)f2b(pa[hh][1].y);
                t[6] = (short)f2b(pa[hh][1].z); t[7] = (short)f2b(pa[hh][1].w);
                *(s8v*)&As[r0 + 64 * hh][p0] = t;
            }
        } else {
            *(s8v*)&As[r0][p0]      = pab[0];
            *(s8v*)&As[r0 + 64][p0] = pab[1];
        }
        *(s8v*)&Bs[r0][p0]      = pb[0];
        *(s8v*)&Bs[r0 + 64][p0] = pb[1];
        __syncthreads();

        if (k0 + 32 < K) prefetch(k0 + 32);   // overlap with compute below

        s8v af[4], bf[4];
#pragma unroll
        for (int i = 0; i < 4; ++i) {
            af[i] = *(const s8v*)&As[wr + 16 * i + l15][lg * 8];
            bf[i] = *(const s8v*)&Bs[wc + 16 * i + l15][lg * 8];
        }
#pragma unroll
        for (int mi = 0; mi < 4; ++mi)
#pragma unroll
            for (int ni = 0; ni < 4; ++ni)
                acc[mi][ni] = mfma_bf16(af[mi], bf[ni], acc[mi][ni]);
        __syncthreads();
    }

    // ---------------- epilogue ----------------
    if constexpr (NORM) {
        if (n0 + wc < 2048) {
            // q or k head: bias + RMSNorm + RoPE, then bf16 store.
            const float* nw = (n0 + wc < 1024) ? qw : kw;
            float wv[4], bv[4];
#pragma unroll
            for (int ni = 0; ni < 4; ++ni) {
                wv[ni] = nw[16 * ni + l15];
                bv[ni] = bias[n0 + wc + 16 * ni + l15];
            }
#pragma unroll
            for (int mi = 0; mi < 4; ++mi) {
#pragma unroll
                for (int r = 0; r < 4; ++r) {
                    int row = m0 + wr + 16 * mi + lg * 4 + r;
                    int s = row & (S_ - 1);
                    float v[4];
#pragma unroll
                    for (int ni = 0; ni < 4; ++ni) v[ni] = acc[mi][ni][r] + bv[ni];
                    float ss = v[0]*v[0] + v[1]*v[1] + v[2]*v[2] + v[3]*v[3];
                    ss += __shfl_xor(ss, 1);
                    ss += __shfl_xor(ss, 2);
                    ss += __shfl_xor(ss, 4);
                    ss += __shfl_xor(ss, 8);
                    float rms = rsqrtf(ss * (1.0f / 64.0f) + 1e-6f);
                    float xn[4];
#pragma unroll
                    for (int ni = 0; ni < 4; ++ni) xn[ni] = v[ni] * rms * wv[ni];
#pragma unroll
                    for (int ni = 0; ni < 4; ++ni) {
                        int d = 16 * ni + l15;
                        float c  = cos_t[s * 64 + d];
                        float sn = sin_t[s * 64 + d];
                        float rot = (ni < 2) ? -xn[ni + 2] : xn[ni - 2];
                        C[(size_t)row * N + n0 + wc + d] = (short)f2b(xn[ni] * c + rot * sn);
                    }
                }
            }
            return;
        }
    }
    // plain path: bias + store
#pragma unroll
    for (int ni = 0; ni < 4; ++ni) {
        float bvv = bias[n0 + wc + 16 * ni + l15];
#pragma unroll
        for (int mi = 0; mi < 4; ++mi) {
#pragma unroll
            for (int r = 0; r < 4; ++r) {
                size_t row = (size_t)(m0 + wr + 16 * mi + lg * 4 + r);
                int    col = n0 + wc + 16 * ni + l15;
                float v = acc[mi][ni][r] + bvv;
                if constexpr (sizeof(CT) == 4) C[row * N + col] = v;
                else                           C[row * N + col] = (short)f2b(v);
            }
        }
    }
}

// ---------------------------------------------------------------------------
// MFMA flash attention with reg-prefetch double buffering.
// Grid (S/128, B*H), 256 thr = 4 waves; wave w owns q rows [q0+32w, +32).
// Swapped QK^T: S^T = mfma(A=K, B=Q). P relayout via per-wave LDS.
// V staged transposed with XOR-swizzled columns (kills 8-way write conflict).
// ---------------------------------------------------------------------------
__global__ __launch_bounds__(256) void attn_mfma(const short* __restrict__ qkv,
                                                 short* __restrict__ attn) {
    __shared__ ushort_t Ks[64][72];        // K-tile  [key][d]
    __shared__ ushort_t Vt[64][72];        // V-tile^T [d][key-swizzled]
    __shared__ ushort_t Ps[4][32][72];     // per-wave P [q_local][key]

    const int tid  = threadIdx.x;
    const int w    = tid >> 6;
    const int lane = tid & 63;
    const int l15  = lane & 15, lg = lane >> 4;
    const int bh = blockIdx.y, b = bh >> 4, h = bh & 15;
    const int q0 = blockIdx.x * 128;

    const short* qbase = qkv + (size_t)b * S_ * TDIM + h * HD_;
    const short* kb = qbase + DIM_;
    const short* vb = qbase + 2 * DIM_;

    // Q fragments (B-operand layout), held for the whole K/V loop
    s8v qf[2][2];
#pragma unroll
    for (int mq = 0; mq < 2; ++mq)
#pragma unroll
        for (int kk = 0; kk < 2; ++kk)
            qf[mq][kk] = *(const s8v*)(qbase + (size_t)(q0 + w * 32 + mq * 16 + l15) * TDIM
                                       + kk * 32 + lg * 8);

    f32x4 of[2][4] = {};
    float m_s[2] = {-1e30f, -1e30f};
    float l_s[2] = {0.f, 0.f};

    const int kr   = tid >> 3;          // K staging row (and +32)
    const int kp8  = (tid & 7) * 8;     // K staging col
    const int vkp  = tid >> 3;          // V key-pair 0..31
    const int va   = tid & 7;           // V d-block 0..7 (vp8 = va*8)
    const int vp8  = va * 8;
    const int vcol = (2 * vkp) ^ ((va & 3) << 4);   // swizzled Vt column

    s8v kA, kB, vA, vB;
    auto prefetch = [&](int kt) {
        const short* kbt = kb + (size_t)kt * 64 * TDIM;
        const short* vbt = vb + (size_t)kt * 64 * TDIM;
        kA = *(const s8v*)(kbt + (size_t)kr * TDIM + kp8);
        kB = *(const s8v*)(kbt + (size_t)(kr + 32) * TDIM + kp8);
        vA = *(const s8v*)(vbt + (size_t)(2 * vkp) * TDIM + vp8);
        vB = *(const s8v*)(vbt + (size_t)(2 * vkp + 1) * TDIM + vp8);
    };
    prefetch(0);

    for (int kt = 0; kt < 16; ++kt) {
        // write prefetched tile -> LDS
        *(s8v*)&Ks[kr][kp8]      = kA;
        *(s8v*)&Ks[kr + 32][kp8] = kB;
#pragma unroll
        for (int j = 0; j < 8; ++j) {
            uint_t pk = (ushort_t)vA[j] | ((uint_t)(ushort_t)vB[j] << 16);
            *(uint_t*)&Vt[vp8 + j][vcol] = pk;
        }
        __syncthreads();

        if (kt < 15) prefetch(kt + 1);     // overlap with compute below

        // ---- QK^T (swapped): st[nk][mq] = S^T[key][q] fragments
        f32x4 st[4][2] = {};
#pragma unroll
        for (int kk = 0; kk < 2; ++kk) {
            s8v kf[4];
#pragma unroll
            for (int nk = 0; nk < 4; ++nk)
                kf[nk] = *(const s8v*)&Ks[nk * 16 + l15][kk * 32 + lg * 8];
#pragma unroll
            for (int nk = 0; nk < 4; ++nk)
#pragma unroll
                for (int mq = 0; mq < 2; ++mq)
                    st[nk][mq] = mfma_bf16(kf[nk], qf[mq][kk], st[nk][mq]);
        }

        // ---- online softmax per q-column (q = 16*mq + l15)
#pragma unroll
        for (int mq = 0; mq < 2; ++mq) {
            float mx = -1e30f;
#pragma unroll
            for (int nk = 0; nk < 4; ++nk)
#pragma unroll
                for (int r = 0; r < 4; ++r) {
                    st[nk][mq][r] *= 0.125f;           // 1/sqrt(HD)
                    mx = fmaxf(mx, st[nk][mq][r]);
                }
            mx = fmaxf(mx, __shfl_xor(mx, 16));
            mx = fmaxf(mx, __shfl_xor(mx, 32));
            float mnew  = fmaxf(m_s[mq], mx);
            float alpha = __expf(m_s[mq] - mnew);
            m_s[mq] = mnew;

            float ls = 0.f;
#pragma unroll
            for (int nk = 0; nk < 4; ++nk) {
#pragma unroll
                for (int r = 0; r < 4; ++r) {
                    float p = __expf(st[nk][mq][r] - mnew);
                    st[nk][mq][r] = p;
                    ls += p;
                }
            }
            ls += __shfl_xor(ls, 16);
            ls += __shfl_xor(ls, 32);
            l_s[mq] = l_s[mq] * alpha + ls;

            // P -> bf16 -> per-wave LDS
#pragma unroll
            for (int nk = 0; nk < 4; ++nk) {
                ushort4 pk;
                pk.x = f2b(st[nk][mq][0]); pk.y = f2b(st[nk][mq][1]);
                pk.z = f2b(st[nk][mq][2]); pk.w = f2b(st[nk][mq][3]);
                *(ushort4*)&Ps[w][mq * 16 + l15][nk * 16 + lg * 4] = pk;
            }

            // rescale O (alpha per-q -> row layout)
            float a4[4];
#pragma unroll
            for (int r = 0; r < 4; ++r) a4[r] = __shfl(alpha, lg * 4 + r);
#pragma unroll
            for (int nd = 0; nd < 4; ++nd)
#pragma unroll
                for (int r = 0; r < 4; ++r) of[mq][nd][r] *= a4[r];
        }

        // ---- PV: O[q][d] += P[q][key] * V[key][d]
#pragma unroll
        for (int kk = 0; kk < 2; ++kk) {
            s8v pf[2], vf[4];
#pragma unroll
            for (int mq = 0; mq < 2; ++mq)
                pf[mq] = *(const s8v*)&Ps[w][mq * 16 + l15][kk * 32 + lg * 8];
#pragma unroll
            for (int nd = 0; nd < 4; ++nd) {
                int swz = (2 * nd + (l15 >> 3)) & 3;
                vf[nd] = *(const s8v*)&Vt[nd * 16 + l15][(kk * 32 + lg * 8) ^ (swz << 4)];
            }
#pragma unroll
            for (int mq = 0; mq < 2; ++mq)
#pragma unroll
                for (int nd = 0; nd < 4; ++nd)
                    of[mq][nd] = mfma_bf16(pf[mq], vf[nd], of[mq][nd]);
        }
        __syncthreads();
    }

    // epilogue: divide by softmax sum, write bf16
#pragma unroll
    for (int mq = 0; mq < 2; ++mq) {
        float rinv = 1.0f / l_s[mq];
        float iv[4];
#pragma unroll
        for (int r = 0; r < 4; ++r) iv[r] = __shfl(rinv, lg * 4 + r);
#pragma unroll
        for (int nd = 0; nd < 4; ++nd)
#pragma unroll
            for (int r = 0; r < 4; ++r) {
                int row = q0 + w * 32 + mq * 16 + lg * 4 + r;
                attn[((size_t)b * S_ + row) * DIM_ + h * HD_ + nd * 16 + l15] =
                    (short)f2b(of[mq][nd][r] * iv[r]);
            }
    }
}

// ---------------------------------------------------------------------------
extern "C" void kernel_launch(void* const* d_in, const int* in_sizes, int n_in,
                              void* d_out, int out_size, void* d_ws, size_t ws_size,
                              hipStream_t stream) {
    const float* x        = (const float*)d_in[0];
    const float* w_qkv    = (const float*)d_in[1];
    const float* b_qkv    = (const float*)d_in[2];
    const float* q_norm_w = (const float*)d_in[3];
    const float* k_norm_w = (const float*)d_in[4];
    const float* w_out    = (const float*)d_in[5];
    const float* b_out    = (const float*)d_in[6];
    float* out = (float*)d_out;

    // workspace layout (~137 MiB)
    const size_t OFF_QKV = 0;                          //  96 MiB: qkv bf16 [16384][3072]
    const size_t OFF_ATT = 100663296;                  //  32 MiB: attn bf16 [16384][1024]
    const size_t OFF_WQ  = OFF_ATT + 33554432;         //   6 MiB: w_qkv^T bf16
    const size_t OFF_WO  = OFF_WQ + 6291456;           //   2 MiB: w_out^T bf16
    const size_t OFF_CT  = OFF_WO + 2097152;           // 256 KiB: cos table
    const size_t OFF_ST  = OFF_CT + 262144;            // 256 KiB: sin table
    const size_t NEED    = OFF_ST + 262144;

    if (ws_size < NEED) {
        hipMemsetAsync(d_out, 0, (size_t)out_size * sizeof(float), stream);
        return;
    }

    char* ws = (char*)d_ws;
    short* qkv   = (short*)(ws + OFF_QKV);
    short* attnb = (short*)(ws + OFF_ATT);
    short* wqkvT = (short*)(ws + OFF_WQ);
    short* woutT = (short*)(ws + OFF_WO);
    float* cos_t = (float*)(ws + OFF_CT);
    float* sin_t = (float*)(ws + OFF_ST);

    // 0: RoPE tables + weight transposes (small)
    rope_tables<<<dim3(256), dim3(256), 0, stream>>>(cos_t, sin_t);
    transpose_to_bf16<<<dim3(96, 32), dim3(256), 0, stream>>>(w_qkv, wqkvT, 1024, 3072);
    transpose_to_bf16<<<dim3(32, 32), dim3(256), 0, stream>>>(w_out, woutT, 1024, 1024);

    // 1: qkv = x @ w_qkv + b_qkv, with fused fp32->bf16 A-staging and fused
    //    RMSNorm+RoPE epilogue on the q,k column range.
    gemm_bf16<short, true, true><<<dim3(24, 128), dim3(256), 0, stream>>>(
        x, wqkvT, b_qkv, qkv, 16384, 3072, 1024,
        q_norm_w, k_norm_w, cos_t, sin_t);

    // 2: flash attention -> attnb (bf16)
    attn_mfma<<<dim3(8, 256), dim3(256), 0, stream>>>(qkv, attnb);

    // 3: out = attn @ w_out + b_out (fp32 out)
    gemm_bf16<float, false, false><<<dim3(8, 128), dim3(256), 0, stream>>>(
        attnb, woutT, b_out, out, 16384, 1024, 1024,
        nullptr, nullptr, nullptr, nullptr);
}

// Round 5
// 346.122 us; speedup vs baseline: 13.9721x; 1.2234x over previous
//
#include <hip/hip_runtime.h>
#include <cstdint>
#include <cstddef>

#define B_    16
#define S_    1024
#define DIM_  1024
#define H_    16
#define HD_   64
#define TDIM  3072   // 3*DIM

typedef unsigned short ushort_t;
typedef unsigned int   uint_t;
typedef __attribute__((ext_vector_type(8))) short s8v;   // 8 bf16 = 4 VGPRs
typedef __attribute__((ext_vector_type(4))) float f32x4;

__device__ __forceinline__ float b2f(ushort_t u) {
    union { uint_t i; float f; } t; t.i = (uint_t)u << 16; return t.f;
}
__device__ __forceinline__ ushort_t f2b(float f) {
    union { float f; uint_t i; } t; t.f = f;
    uint_t r = t.i + 0x7FFFu + ((t.i >> 16) & 1u);   // RNE
    return (ushort_t)(r >> 16);
}

// D[m][n] += sum_k A[m,k]*B[k,n].
// A-frag: lane&15=m, (lane>>4)*8+j=k. B-frag: lane&15=n, same k.
// D-frag (HW-verified m89/m91): col=lane&15, row=(lane>>4)*4+reg.
__device__ __forceinline__ f32x4 mfma_bf16(s8v a, s8v b, f32x4 c) {
    asm volatile("v_mfma_f32_16x16x32_bf16 %0, %1, %2, %0" : "+v"(c) : "v"(a), "v"(b));
    return c;
}

// async global->LDS, 16B per lane; LDS dest = wave-uniform base + lane*16.
__device__ __forceinline__ void gload16(const void* g, void* l) {
    __builtin_amdgcn_global_load_lds(
        (const __attribute__((address_space(1))) uint_t*)g,
        (__attribute__((address_space(3))) uint_t*)l, 16, 0, 0);
}

// ---------------------------------------------------------------------------
// fp32 -> bf16, 8 elements/thread
// ---------------------------------------------------------------------------
__global__ __launch_bounds__(256) void f32_to_bf16_vec(const float* __restrict__ src,
                                                       short* __restrict__ dst, int n8) {
    int i = blockIdx.x * 256 + threadIdx.x;
    if (i < n8) {
        float4 a = *(const float4*)(src + (size_t)i * 8);
        float4 b = *(const float4*)(src + (size_t)i * 8 + 4);
        s8v t;
        t[0] = (short)f2b(a.x); t[1] = (short)f2b(a.y);
        t[2] = (short)f2b(a.z); t[3] = (short)f2b(a.w);
        t[4] = (short)f2b(b.x); t[5] = (short)f2b(b.y);
        t[6] = (short)f2b(b.z); t[7] = (short)f2b(b.w);
        *(s8v*)(dst + (size_t)i * 8) = t;
    }
}

// ---------------------------------------------------------------------------
// RoPE cos/sin tables [S][HD] fp32 (512 KB, L2/L3-resident).
// ---------------------------------------------------------------------------
__global__ __launch_bounds__(256) void rope_tables(float* __restrict__ cos_t,
                                                   float* __restrict__ sin_t) {
    int idx = blockIdx.x * 256 + threadIdx.x;     // 0 .. 65535
    int s = idx >> 6;
    int d = idx & 63;
    int pos = (d < 32) ? (s >> 5) : (s & 31);
    int i   = (d & 31) >> 1;
    float freq  = expf(-(float)i * 0.5756462732485115f);   // ln(10000)/16
    float angle = (float)pos * 0.5f * freq;
    cos_t[idx] = cosf(angle);
    sin_t[idx] = sinf(angle);
}

// ---------------------------------------------------------------------------
// W[K][N] fp32 -> WT[N][K] bf16  (32x32 LDS tile transpose)
// ---------------------------------------------------------------------------
__global__ __launch_bounds__(256) void transpose_to_bf16(const float* __restrict__ Wsrc,
                                                         short* __restrict__ WT,
                                                         int K, int N) {
    __shared__ float t[32][33];
    int tx = threadIdx.x & 31, ty = threadIdx.x >> 5;   // ty 0..7
    int n0 = blockIdx.x * 32, k0 = blockIdx.y * 32;
#pragma unroll
    for (int i = 0; i < 4; ++i)
        t[ty + 8 * i][tx] = Wsrc[(size_t)(k0 + ty + 8 * i) * N + n0 + tx];
    __syncthreads();
#pragma unroll
    for (int i = 0; i < 4; ++i)
        WT[(size_t)(n0 + ty + 8 * i) * K + k0 + tx] = (short)f2b(t[tx][ty + 8 * i]);
}

// ---------------------------------------------------------------------------
// bf16 MFMA GEMM, m97 structure: 128x128 tile, BK=64, linear LDS,
// global_load_lds width-16 staging, 4 waves, 4x4 frags/wave, 2 barriers/K-step.
//   C[M,N] = A[M,K] @ B[K,N] + bias, B given as BT[N,K]. A,BT bf16.
//   NORM: fused per-head RMSNorm + RoPE epilogue for columns < 2048 (q,k).
// 1-D grid with bijective XCD-chunked remap (launch guarantees nwg % 8 == 0).
// ---------------------------------------------------------------------------
template<typename CT, bool NORM>
__global__ __launch_bounds__(256) void gemm_glds(
        const short* __restrict__ A, const short* __restrict__ BT,
        const float* __restrict__ bias, CT* __restrict__ C,
        int M, int N, int K, int NX,
        const float* __restrict__ qw, const float* __restrict__ kw,
        const float* __restrict__ cos_t, const float* __restrict__ sin_t) {
    __shared__ short As[128 * 64];   // [row][k] linear, 16 KiB
    __shared__ short Bs[128 * 64];

    const int tid  = threadIdx.x;
    const int w    = tid >> 6;
    const int lane = tid & 63;
    const int l15  = lane & 15, lg = lane >> 4;

    // XCD-chunked remap of the 1-D grid (bijective since nwg % 8 == 0)
    const int nwg  = gridDim.x;
    const int cpx  = nwg >> 3;
    const int wgid = (blockIdx.x & 7) * cpx + (blockIdx.x >> 3);
    const int bx = wgid % NX, by = wgid / NX;
    const int m0 = by * 128, n0 = bx * 128;
    const int wr = (w >> 1) * 64, wc = (w & 1) * 64;

    // staging geometry: wave w, instr i covers rows w*32+i*8 .. +8.
    // lane l -> row +(l>>3), 16B chunk (l&7). LDS dest = uniform base+lane*16.
    const int srow = w * 32 + (lane >> 3);
    const int sk   = (lane & 7) * 8;

    f32x4 acc[4][4] = {};

    for (int k0 = 0; k0 < K; k0 += 64) {
        __syncthreads();   // all waves done reading previous tile
#pragma unroll
        for (int i = 0; i < 4; ++i) {
            int r = srow + i * 8;
            gload16(A  + (size_t)(m0 + r) * K + k0 + sk, &As[(w * 4 + i) * 512]);
            gload16(BT + (size_t)(n0 + r) * K + k0 + sk, &Bs[(w * 4 + i) * 512]);
        }
        __syncthreads();   // drains vmcnt(0): tile visible

#pragma unroll
        for (int kk = 0; kk < 2; ++kk) {
            s8v af[4], bf[4];
#pragma unroll
            for (int i = 0; i < 4; ++i) {
                af[i] = *(const s8v*)&As[(wr + 16 * i + l15) * 64 + kk * 32 + lg * 8];
                bf[i] = *(const s8v*)&Bs[(wc + 16 * i + l15) * 64 + kk * 32 + lg * 8];
            }
#pragma unroll
            for (int mi = 0; mi < 4; ++mi)
#pragma unroll
                for (int ni = 0; ni < 4; ++ni)
                    acc[mi][ni] = mfma_bf16(af[mi], bf[ni], acc[mi][ni]);
        }
    }

    // ---------------- epilogue ----------------
    if constexpr (NORM) {
        if (n0 + wc < 2048) {
            // q or k head: bias + RMSNorm + RoPE, then bf16 store.
            const float* nw = (n0 + wc < 1024) ? qw : kw;
            float wv[4], bv[4];
#pragma unroll
            for (int ni = 0; ni < 4; ++ni) {
                wv[ni] = nw[16 * ni + l15];
                bv[ni] = bias[n0 + wc + 16 * ni + l15];
            }
#pragma unroll
            for (int mi = 0; mi < 4; ++mi) {
#pragma unroll
                for (int r = 0; r < 4; ++r) {
                    int row = m0 + wr + 16 * mi + lg * 4 + r;
                    int s = row & (S_ - 1);
                    float v[4];
#pragma unroll
                    for (int ni = 0; ni < 4; ++ni) v[ni] = acc[mi][ni][r] + bv[ni];
                    float ss = v[0]*v[0] + v[1]*v[1] + v[2]*v[2] + v[3]*v[3];
                    ss += __shfl_xor(ss, 1);
                    ss += __shfl_xor(ss, 2);
                    ss += __shfl_xor(ss, 4);
                    ss += __shfl_xor(ss, 8);
                    float rms = rsqrtf(ss * (1.0f / 64.0f) + 1e-6f);
                    float xn[4];
#pragma unroll
                    for (int ni = 0; ni < 4; ++ni) xn[ni] = v[ni] * rms * wv[ni];
#pragma unroll
                    for (int ni = 0; ni < 4; ++ni) {
                        int d = 16 * ni + l15;
                        float c  = cos_t[s * 64 + d];
                        float sn = sin_t[s * 64 + d];
                        float rot = (ni < 2) ? -xn[ni + 2] : xn[ni - 2];
                        C[(size_t)row * N + n0 + wc + d] = (short)f2b(xn[ni] * c + rot * sn);
                    }
                }
            }
            return;
        }
    }
    // plain path: bias + store
#pragma unroll
    for (int ni = 0; ni < 4; ++ni) {
        float bvv = bias[n0 + wc + 16 * ni + l15];
#pragma unroll
        for (int mi = 0; mi < 4; ++mi) {
#pragma unroll
            for (int r = 0; r < 4; ++r) {
                size_t row = (size_t)(m0 + wr + 16 * mi + lg * 4 + r);
                int    col = n0 + wc + 16 * ni + l15;
                float v = acc[mi][ni][r] + bvv;
                if constexpr (sizeof(CT) == 4) C[row * N + col] = v;
                else                           C[row * N + col] = (short)f2b(v);
            }
        }
    }
}

// ---------------------------------------------------------------------------
// MFMA flash attention with reg-prefetch double buffering (round-4 version).
// Grid (S/128, B*H), 256 thr = 4 waves; wave w owns q rows [q0+32w, +32).
// Swapped QK^T: S^T = mfma(A=K, B=Q). P relayout via per-wave LDS.
// V staged transposed with XOR-swizzled columns.
// ---------------------------------------------------------------------------
__global__ __launch_bounds__(256) void attn_mfma(const short* __restrict__ qkv,
                                                 short* __restrict__ attn) {
    __shared__ ushort_t Ks[64][72];        // K-tile  [key][d]
    __shared__ ushort_t Vt[64][72];        // V-tile^T [d][key-swizzled]
    __shared__ ushort_t Ps[4][32][72];     // per-wave P [q_local][key]

    const int tid  = threadIdx.x;
    const int w    = tid >> 6;
    const int lane = tid & 63;
    const int l15  = lane & 15, lg = lane >> 4;
    const int bh = blockIdx.y, b = bh >> 4, h = bh & 15;
    const int q0 = blockIdx.x * 128;

    const short* qbase = qkv + (size_t)b * S_ * TDIM + h * HD_;
    const short* kb = qbase + DIM_;
    const short* vb = qbase + 2 * DIM_;

    // Q fragments (B-operand layout), held for the whole K/V loop
    s8v qf[2][2];
#pragma unroll
    for (int mq = 0; mq < 2; ++mq)
#pragma unroll
        for (int kk = 0; kk < 2; ++kk)
            qf[mq][kk] = *(const s8v*)(qbase + (size_t)(q0 + w * 32 + mq * 16 + l15) * TDIM
                                       + kk * 32 + lg * 8);

    f32x4 of[2][4] = {};
    float m_s[2] = {-1e30f, -1e30f};
    float l_s[2] = {0.f, 0.f};

    const int kr   = tid >> 3;          // K staging row (and +32)
    const int kp8  = (tid & 7) * 8;     // K staging col
    const int vkp  = tid >> 3;          // V key-pair 0..31
    const int va   = tid & 7;           // V d-block 0..7
    const int vp8  = va * 8;
    const int vcol = (2 * vkp) ^ ((va & 3) << 4);   // swizzled Vt column

    s8v kA, kB, vA, vB;
    auto prefetch = [&](int kt) {
        const short* kbt = kb + (size_t)kt * 64 * TDIM;
        const short* vbt = vb + (size_t)kt * 64 * TDIM;
        kA = *(const s8v*)(kbt + (size_t)kr * TDIM + kp8);
        kB = *(const s8v*)(kbt + (size_t)(kr + 32) * TDIM + kp8);
        vA = *(const s8v*)(vbt + (size_t)(2 * vkp) * TDIM + vp8);
        vB = *(const s8v*)(vbt + (size_t)(2 * vkp + 1) * TDIM + vp8);
    };
    prefetch(0);

    for (int kt = 0; kt < 16; ++kt) {
        *(s8v*)&Ks[kr][kp8]      = kA;
        *(s8v*)&Ks[kr + 32][kp8] = kB;
#pragma unroll
        for (int j = 0; j < 8; ++j) {
            uint_t pk = (ushort_t)vA[j] | ((uint_t)(ushort_t)vB[j] << 16);
            *(uint_t*)&Vt[vp8 + j][vcol] = pk;
        }
        __syncthreads();

        if (kt < 15) prefetch(kt + 1);     // overlap with compute below

        // ---- QK^T (swapped): st[nk][mq] = S^T[key][q] fragments
        f32x4 st[4][2] = {};
#pragma unroll
        for (int kk = 0; kk < 2; ++kk) {
            s8v kf[4];
#pragma unroll
            for (int nk = 0; nk < 4; ++nk)
                kf[nk] = *(const s8v*)&Ks[nk * 16 + l15][kk * 32 + lg * 8];
#pragma unroll
            for (int nk = 0; nk < 4; ++nk)
#pragma unroll
                for (int mq = 0; mq < 2; ++mq)
                    st[nk][mq] = mfma_bf16(kf[nk], qf[mq][kk], st[nk][mq]);
        }

        // ---- online softmax per q-column (q = 16*mq + l15)
#pragma unroll
        for (int mq = 0; mq < 2; ++mq) {
            float mx = -1e30f;
#pragma unroll
            for (int nk = 0; nk < 4; ++nk)
#pragma unroll
                for (int r = 0; r < 4; ++r) {
                    st[nk][mq][r] *= 0.125f;           // 1/sqrt(HD)
                    mx = fmaxf(mx, st[nk][mq][r]);
                }
            mx = fmaxf(mx, __shfl_xor(mx, 16));
            mx = fmaxf(mx, __shfl_xor(mx, 32));
            float mnew  = fmaxf(m_s[mq], mx);
            float alpha = __expf(m_s[mq] - mnew);
            m_s[mq] = mnew;

            float ls = 0.f;
#pragma unroll
            for (int nk = 0; nk < 4; ++nk) {
#pragma unroll
                for (int r = 0; r < 4; ++r) {
                    float p = __expf(st[nk][mq][r] - mnew);
                    st[nk][mq][r] = p;
                    ls += p;
                }
            }
            ls += __shfl_xor(ls, 16);
            ls += __shfl_xor(ls, 32);
            l_s[mq] = l_s[mq] * alpha + ls;

            // P -> bf16 -> per-wave LDS
#pragma unroll
            for (int nk = 0; nk < 4; ++nk) {
                ushort4 pk;
                pk.x = f2b(st[nk][mq][0]); pk.y = f2b(st[nk][mq][1]);
                pk.z = f2b(st[nk][mq][2]); pk.w = f2b(st[nk][mq][3]);
                *(ushort4*)&Ps[w][mq * 16 + l15][nk * 16 + lg * 4] = pk;
            }

            // rescale O (alpha per-q -> row layout)
            float a4[4];
#pragma unroll
            for (int r = 0; r < 4; ++r) a4[r] = __shfl(alpha, lg * 4 + r);
#pragma unroll
            for (int nd = 0; nd < 4; ++nd)
#pragma unroll
                for (int r = 0; r < 4; ++r) of[mq][nd][r] *= a4[r];
        }

        // ---- PV: O[q][d] += P[q][key] * V[key][d]
#pragma unroll
        for (int kk = 0; kk < 2; ++kk) {
            s8v pf[2], vf[4];
#pragma unroll
            for (int mq = 0; mq < 2; ++mq)
                pf[mq] = *(const s8v*)&Ps[w][mq * 16 + l15][kk * 32 + lg * 8];
#pragma unroll
            for (int nd = 0; nd < 4; ++nd) {
                int swz = (2 * nd + (l15 >> 3)) & 3;
                vf[nd] = *(const s8v*)&Vt[nd * 16 + l15][(kk * 32 + lg * 8) ^ (swz << 4)];
            }
#pragma unroll
            for (int mq = 0; mq < 2; ++mq)
#pragma unroll
                for (int nd = 0; nd < 4; ++nd)
                    of[mq][nd] = mfma_bf16(pf[mq], vf[nd], of[mq][nd]);
        }
        __syncthreads();
    }

    // epilogue: divide by softmax sum, write bf16
#pragma unroll
    for (int mq = 0; mq < 2; ++mq) {
        float rinv = 1.0f / l_s[mq];
        float iv[4];
#pragma unroll
        for (int r = 0; r < 4; ++r) iv[r] = __shfl(rinv, lg * 4 + r);
#pragma unroll
        for (int nd = 0; nd < 4; ++nd)
#pragma unroll
            for (int r = 0; r < 4; ++r) {
                int row = q0 + w * 32 + mq * 16 + lg * 4 + r;
                attn[((size_t)b * S_ + row) * DIM_ + h * HD_ + nd * 16 + l15] =
                    (short)f2b(of[mq][nd][r] * iv[r]);
            }
    }
}

// ---------------------------------------------------------------------------
extern "C" void kernel_launch(void* const* d_in, const int* in_sizes, int n_in,
                              void* d_out, int out_size, void* d_ws, size_t ws_size,
                              hipStream_t stream) {
    const float* x        = (const float*)d_in[0];
    const float* w_qkv    = (const float*)d_in[1];
    const float* b_qkv    = (const float*)d_in[2];
    const float* q_norm_w = (const float*)d_in[3];
    const float* k_norm_w = (const float*)d_in[4];
    const float* w_out    = (const float*)d_in[5];
    const float* b_out    = (const float*)d_in[6];
    float* out = (float*)d_out;

    // workspace layout (~170 MiB)
    const size_t OFF_QKV = 0;                          //  96 MiB: qkv bf16 [16384][3072]
    const size_t OFF_ATT = 100663296;                  //  32 MiB: attn bf16 [16384][1024]
    const size_t OFF_XB  = OFF_ATT + 33554432;         //  32 MiB: x bf16 [16384][1024]
    const size_t OFF_WQ  = OFF_XB + 33554432;          //   6 MiB: w_qkv^T bf16
    const size_t OFF_WO  = OFF_WQ + 6291456;           //   2 MiB: w_out^T bf16
    const size_t OFF_CT  = OFF_WO + 2097152;           // 256 KiB: cos table
    const size_t OFF_ST  = OFF_CT + 262144;            // 256 KiB: sin table
    const size_t NEED    = OFF_ST + 262144;

    if (ws_size < NEED) {
        hipMemsetAsync(d_out, 0, (size_t)out_size * sizeof(float), stream);
        return;
    }

    char* ws = (char*)d_ws;
    short* qkv   = (short*)(ws + OFF_QKV);
    short* attnb = (short*)(ws + OFF_ATT);
    short* xb    = (short*)(ws + OFF_XB);
    short* wqkvT = (short*)(ws + OFF_WQ);
    short* woutT = (short*)(ws + OFF_WO);
    float* cos_t = (float*)(ws + OFF_CT);
    float* sin_t = (float*)(ws + OFF_ST);

    // 0: tables, conversions, weight transposes
    rope_tables<<<dim3(256), dim3(256), 0, stream>>>(cos_t, sin_t);
    f32_to_bf16_vec<<<dim3(8192), dim3(256), 0, stream>>>(x, xb, 2097152);
    transpose_to_bf16<<<dim3(96, 32), dim3(256), 0, stream>>>(w_qkv, wqkvT, 1024, 3072);
    transpose_to_bf16<<<dim3(32, 32), dim3(256), 0, stream>>>(w_out, woutT, 1024, 1024);

    // 1: qkv = x @ w_qkv + b_qkv, fused RMSNorm+RoPE epilogue on q,k columns.
    //    grid = 24*128 = 3072 blocks (nwg % 8 == 0)
    gemm_glds<short, true><<<dim3(3072), dim3(256), 0, stream>>>(
        xb, wqkvT, b_qkv, qkv, 16384, 3072, 1024, 24,
        q_norm_w, k_norm_w, cos_t, sin_t);

    // 2: flash attention -> attnb (bf16)
    attn_mfma<<<dim3(8, 256), dim3(256), 0, stream>>>(qkv, attnb);

    // 3: out = attn @ w_out + b_out (fp32 out), grid = 8*128 = 1024 blocks
    gemm_glds<float, false><<<dim3(1024), dim3(256), 0, stream>>>(
        attnb, woutT, b_out, out, 16384, 1024, 1024, 8,
        nullptr, nullptr, nullptr, nullptr);
}

// Round 6
// 346.085 us; speedup vs baseline: 13.9736x; 1.0001x over previous
//
#include <hip/hip_runtime.h>
#include <cstdint>
#include <cstddef>

#define B_    16
#define S_    1024
#define DIM_  1024
#define H_    16
#define HD_   64
#define TDIM  3072   // 3*DIM

typedef unsigned short ushort_t;
typedef unsigned int   uint_t;
typedef __attribute__((ext_vector_type(8))) short s8v;   // 8 bf16 = 4 VGPRs
typedef __attribute__((ext_vector_type(4))) float f32x4;

__device__ __forceinline__ float b2f(ushort_t u) {
    union { uint_t i; float f; } t; t.i = (uint_t)u << 16; return t.f;
}
__device__ __forceinline__ ushort_t f2b(float f) {
    union { float f; uint_t i; } t; t.f = f;
    uint_t r = t.i + 0x7FFFu + ((t.i >> 16) & 1u);   // RNE
    return (ushort_t)(r >> 16);
}
// pack two f32 -> u32 of 2 bf16 (lo = a, hi = b)
__device__ __forceinline__ uint_t cvt_pk_bf16(float a, float b) {
    uint_t r;
    asm("v_cvt_pk_bf16_f32 %0, %1, %2" : "=v"(r) : "v"(a), "v"(b));
    return r;
}

// D[m][n] += sum_k A[m,k]*B[k,n].
// A-frag: lane&15=m, (lane>>4)*8+j=k. B-frag: lane&15=n, same k.
// D-frag (HW-verified m89/m91): col=lane&15, row=(lane>>4)*4+reg.
__device__ __forceinline__ f32x4 mfma_bf16(s8v a, s8v b, f32x4 c) {
    asm volatile("v_mfma_f32_16x16x32_bf16 %0, %1, %2, %0" : "+v"(c) : "v"(a), "v"(b));
    return c;
}

// async global->LDS, 16B per lane; LDS dest = wave-uniform base + lane*16.
__device__ __forceinline__ void gload16(const void* g, void* l) {
    __builtin_amdgcn_global_load_lds(
        (const __attribute__((address_space(1))) uint_t*)g,
        (__attribute__((address_space(3))) uint_t*)l, 16, 0, 0);
}

// ---------------------------------------------------------------------------
// fp32 -> bf16, 8 elements/thread
// ---------------------------------------------------------------------------
__global__ __launch_bounds__(256) void f32_to_bf16_vec(const float* __restrict__ src,
                                                       short* __restrict__ dst, int n8) {
    int i = blockIdx.x * 256 + threadIdx.x;
    if (i < n8) {
        float4 a = *(const float4*)(src + (size_t)i * 8);
        float4 b = *(const float4*)(src + (size_t)i * 8 + 4);
        s8v t;
        t[0] = (short)f2b(a.x); t[1] = (short)f2b(a.y);
        t[2] = (short)f2b(a.z); t[3] = (short)f2b(a.w);
        t[4] = (short)f2b(b.x); t[5] = (short)f2b(b.y);
        t[6] = (short)f2b(b.z); t[7] = (short)f2b(b.w);
        *(s8v*)(dst + (size_t)i * 8) = t;
    }
}

// ---------------------------------------------------------------------------
// RoPE cos/sin tables [S][HD] fp32 (512 KB, L2/L3-resident).
// ---------------------------------------------------------------------------
__global__ __launch_bounds__(256) void rope_tables(float* __restrict__ cos_t,
                                                   float* __restrict__ sin_t) {
    int idx = blockIdx.x * 256 + threadIdx.x;     // 0 .. 65535
    int s = idx >> 6;
    int d = idx & 63;
    int pos = (d < 32) ? (s >> 5) : (s & 31);
    int i   = (d & 31) >> 1;
    float freq  = expf(-(float)i * 0.5756462732485115f);   // ln(10000)/16
    float angle = (float)pos * 0.5f * freq;
    cos_t[idx] = cosf(angle);
    sin_t[idx] = sinf(angle);
}

// ---------------------------------------------------------------------------
// W[K][N] fp32 -> WT[N][K] bf16  (32x32 LDS tile transpose)
// ---------------------------------------------------------------------------
__global__ __launch_bounds__(256) void transpose_to_bf16(const float* __restrict__ Wsrc,
                                                         short* __restrict__ WT,
                                                         int K, int N) {
    __shared__ float t[32][33];
    int tx = threadIdx.x & 31, ty = threadIdx.x >> 5;   // ty 0..7
    int n0 = blockIdx.x * 32, k0 = blockIdx.y * 32;
#pragma unroll
    for (int i = 0; i < 4; ++i)
        t[ty + 8 * i][tx] = Wsrc[(size_t)(k0 + ty + 8 * i) * N + n0 + tx];
    __syncthreads();
#pragma unroll
    for (int i = 0; i < 4; ++i)
        WT[(size_t)(n0 + ty + 8 * i) * K + k0 + tx] = (short)f2b(t[tx][ty + 8 * i]);
}

// ---------------------------------------------------------------------------
// bf16 MFMA GEMM, m97 structure: 128x128 tile, BK=64, linear LDS,
// global_load_lds width-16 staging, 4 waves, 4x4 frags/wave, 2 barriers/K-step.
//   C[M,N] = A[M,K] @ B[K,N] + bias, B given as BT[N,K]. A,BT bf16.
//   NORM: fused per-head RMSNorm + RoPE epilogue for columns < 2048 (q,k).
// 1-D grid with bijective XCD-chunked remap (launch guarantees nwg % 8 == 0).
// ---------------------------------------------------------------------------
template<typename CT, bool NORM>
__global__ __launch_bounds__(256) void gemm_glds(
        const short* __restrict__ A, const short* __restrict__ BT,
        const float* __restrict__ bias, CT* __restrict__ C,
        int M, int N, int K, int NX,
        const float* __restrict__ qw, const float* __restrict__ kw,
        const float* __restrict__ cos_t, const float* __restrict__ sin_t) {
    __shared__ short As[128 * 64];   // [row][k] linear, 16 KiB
    __shared__ short Bs[128 * 64];

    const int tid  = threadIdx.x;
    const int w    = tid >> 6;
    const int lane = tid & 63;
    const int l15  = lane & 15, lg = lane >> 4;

    // XCD-chunked remap of the 1-D grid (bijective since nwg % 8 == 0)
    const int nwg  = gridDim.x;
    const int cpx  = nwg >> 3;
    const int wgid = (blockIdx.x & 7) * cpx + (blockIdx.x >> 3);
    const int bx = wgid % NX, by = wgid / NX;
    const int m0 = by * 128, n0 = bx * 128;
    const int wr = (w >> 1) * 64, wc = (w & 1) * 64;

    // staging geometry: wave w, instr i covers rows w*32+i*8 .. +8.
    const int srow = w * 32 + (lane >> 3);
    const int sk   = (lane & 7) * 8;

    f32x4 acc[4][4] = {};

    for (int k0 = 0; k0 < K; k0 += 64) {
        __syncthreads();   // all waves done reading previous tile
#pragma unroll
        for (int i = 0; i < 4; ++i) {
            int r = srow + i * 8;
            gload16(A  + (size_t)(m0 + r) * K + k0 + sk, &As[(w * 4 + i) * 512]);
            gload16(BT + (size_t)(n0 + r) * K + k0 + sk, &Bs[(w * 4 + i) * 512]);
        }
        __syncthreads();   // drains vmcnt(0): tile visible

#pragma unroll
        for (int kk = 0; kk < 2; ++kk) {
            s8v af[4], bf[4];
#pragma unroll
            for (int i = 0; i < 4; ++i) {
                af[i] = *(const s8v*)&As[(wr + 16 * i + l15) * 64 + kk * 32 + lg * 8];
                bf[i] = *(const s8v*)&Bs[(wc + 16 * i + l15) * 64 + kk * 32 + lg * 8];
            }
#pragma unroll
            for (int mi = 0; mi < 4; ++mi)
#pragma unroll
                for (int ni = 0; ni < 4; ++ni)
                    acc[mi][ni] = mfma_bf16(af[mi], bf[ni], acc[mi][ni]);
        }
    }

    // ---------------- epilogue ----------------
    if constexpr (NORM) {
        if (n0 + wc < 2048) {
            // q or k head: bias + RMSNorm + RoPE, then bf16 store.
            const float* nw = (n0 + wc < 1024) ? qw : kw;
            float wv[4], bv[4];
#pragma unroll
            for (int ni = 0; ni < 4; ++ni) {
                wv[ni] = nw[16 * ni + l15];
                bv[ni] = bias[n0 + wc + 16 * ni + l15];
            }
#pragma unroll
            for (int mi = 0; mi < 4; ++mi) {
#pragma unroll
                for (int r = 0; r < 4; ++r) {
                    int row = m0 + wr + 16 * mi + lg * 4 + r;
                    int s = row & (S_ - 1);
                    float v[4];
#pragma unroll
                    for (int ni = 0; ni < 4; ++ni) v[ni] = acc[mi][ni][r] + bv[ni];
                    float ss = v[0]*v[0] + v[1]*v[1] + v[2]*v[2] + v[3]*v[3];
                    ss += __shfl_xor(ss, 1);
                    ss += __shfl_xor(ss, 2);
                    ss += __shfl_xor(ss, 4);
                    ss += __shfl_xor(ss, 8);
                    float rms = rsqrtf(ss * (1.0f / 64.0f) + 1e-6f);
                    float xn[4];
#pragma unroll
                    for (int ni = 0; ni < 4; ++ni) xn[ni] = v[ni] * rms * wv[ni];
#pragma unroll
                    for (int ni = 0; ni < 4; ++ni) {
                        int d = 16 * ni + l15;
                        float c  = cos_t[s * 64 + d];
                        float sn = sin_t[s * 64 + d];
                        float rot = (ni < 2) ? -xn[ni + 2] : xn[ni - 2];
                        C[(size_t)row * N + n0 + wc + d] = (short)f2b(xn[ni] * c + rot * sn);
                    }
                }
            }
            return;
        }
    }
    // plain path: bias + store
#pragma unroll
    for (int ni = 0; ni < 4; ++ni) {
        float bvv = bias[n0 + wc + 16 * ni + l15];
#pragma unroll
        for (int mi = 0; mi < 4; ++mi) {
#pragma unroll
            for (int r = 0; r < 4; ++r) {
                size_t row = (size_t)(m0 + wr + 16 * mi + lg * 4 + r);
                int    col = n0 + wc + 16 * ni + l15;
                float v = acc[mi][ni][r] + bvv;
                if constexpr (sizeof(CT) == 4) C[row * N + col] = v;
                else                           C[row * N + col] = (short)f2b(v);
            }
        }
    }
}

// ---------------------------------------------------------------------------
// MFMA flash attention, VALU-trimmed softmax:
//   - logits kept raw; running max m_s in exp2-scaled units (SC = 0.125*log2e)
//   - P = exp2(st*SC - m_s) via fma+v_exp (v_exp_f32 is natively 2^x)
//   - T13 defer-max: skip alpha/rescale when tile max within THR of running max
//   - P -> bf16 via v_cvt_pk_bf16_f32 (T12), stored as uint2
//   - T5 setprio around MFMA clusters
// Grid (S/128, B*H), 256 thr = 4 waves; wave w owns q rows [q0+32w, +32).
// Swapped QK^T: S^T = mfma(A=K, B=Q). P relayout via per-wave LDS.
// ---------------------------------------------------------------------------
__global__ __launch_bounds__(256) void attn_mfma(const short* __restrict__ qkv,
                                                 short* __restrict__ attn) {
    __shared__ ushort_t Ks[64][72];        // K-tile  [key][d]
    __shared__ ushort_t Vt[64][72];        // V-tile^T [d][key-swizzled]
    __shared__ ushort_t Ps[4][32][72];     // per-wave P [q_local][key]

    const float SC  = 0.18033688011112042f;   // 0.125 * log2(e)
    const float THR = 11.0f;                  // defer-max threshold (exp2 units)

    const int tid  = threadIdx.x;
    const int w    = tid >> 6;
    const int lane = tid & 63;
    const int l15  = lane & 15, lg = lane >> 4;
    const int bh = blockIdx.y, b = bh >> 4, h = bh & 15;
    const int q0 = blockIdx.x * 128;

    const short* qbase = qkv + (size_t)b * S_ * TDIM + h * HD_;
    const short* kb = qbase + DIM_;
    const short* vb = qbase + 2 * DIM_;

    // Q fragments (B-operand layout), held for the whole K/V loop
    s8v qf[2][2];
#pragma unroll
    for (int mq = 0; mq < 2; ++mq)
#pragma unroll
        for (int kk = 0; kk < 2; ++kk)
            qf[mq][kk] = *(const s8v*)(qbase + (size_t)(q0 + w * 32 + mq * 16 + l15) * TDIM
                                       + kk * 32 + lg * 8);

    f32x4 of[2][4] = {};
    float m_s[2] = {-1e30f, -1e30f};
    float l_s[2] = {0.f, 0.f};

    const int kr   = tid >> 3;          // K staging row (and +32)
    const int kp8  = (tid & 7) * 8;     // K staging col
    const int vkp  = tid >> 3;          // V key-pair 0..31
    const int va   = tid & 7;           // V d-block 0..7
    const int vp8  = va * 8;
    const int vcol = (2 * vkp) ^ ((va & 3) << 4);   // swizzled Vt column

    s8v kA, kB, vA, vB;
    auto prefetch = [&](int kt) {
        const short* kbt = kb + (size_t)kt * 64 * TDIM;
        const short* vbt = vb + (size_t)kt * 64 * TDIM;
        kA = *(const s8v*)(kbt + (size_t)kr * TDIM + kp8);
        kB = *(const s8v*)(kbt + (size_t)(kr + 32) * TDIM + kp8);
        vA = *(const s8v*)(vbt + (size_t)(2 * vkp) * TDIM + vp8);
        vB = *(const s8v*)(vbt + (size_t)(2 * vkp + 1) * TDIM + vp8);
    };
    prefetch(0);

    for (int kt = 0; kt < 16; ++kt) {
        *(s8v*)&Ks[kr][kp8]      = kA;
        *(s8v*)&Ks[kr + 32][kp8] = kB;
#pragma unroll
        for (int j = 0; j < 8; ++j) {
            uint_t pk = (ushort_t)vA[j] | ((uint_t)(ushort_t)vB[j] << 16);
            *(uint_t*)&Vt[vp8 + j][vcol] = pk;
        }
        __syncthreads();

        if (kt < 15) prefetch(kt + 1);     // overlap with compute below

        // ---- QK^T (swapped): st[nk][mq] = S^T[key][q] fragments (raw logits)
        f32x4 st[4][2] = {};
        __builtin_amdgcn_s_setprio(1);
#pragma unroll
        for (int kk = 0; kk < 2; ++kk) {
            s8v kf[4];
#pragma unroll
            for (int nk = 0; nk < 4; ++nk)
                kf[nk] = *(const s8v*)&Ks[nk * 16 + l15][kk * 32 + lg * 8];
#pragma unroll
            for (int nk = 0; nk < 4; ++nk)
#pragma unroll
                for (int mq = 0; mq < 2; ++mq)
                    st[nk][mq] = mfma_bf16(kf[nk], qf[mq][kk], st[nk][mq]);
        }
        __builtin_amdgcn_s_setprio(0);

        // ---- online softmax per q-column (q = 16*mq + l15), exp2 domain
#pragma unroll
        for (int mq = 0; mq < 2; ++mq) {
            float mx = -1e30f;
#pragma unroll
            for (int nk = 0; nk < 4; ++nk)
#pragma unroll
                for (int r = 0; r < 4; ++r)
                    mx = fmaxf(mx, st[nk][mq][r]);
            mx = fmaxf(mx, __shfl_xor(mx, 16));
            mx = fmaxf(mx, __shfl_xor(mx, 32));
            float mxs = mx * SC;

            if (!__all(mxs <= m_s[mq] + THR)) {      // wave-uniform branch
                float mnew  = fmaxf(m_s[mq], mxs);
                float alpha = exp2f(m_s[mq] - mnew);
                m_s[mq] = mnew;
                l_s[mq] *= alpha;
                float a4[4];
#pragma unroll
                for (int r = 0; r < 4; ++r) a4[r] = __shfl(alpha, lg * 4 + r);
#pragma unroll
                for (int nd = 0; nd < 4; ++nd)
#pragma unroll
                    for (int r = 0; r < 4; ++r) of[mq][nd][r] *= a4[r];
            }

            float m = m_s[mq];
            float ls = 0.f;
#pragma unroll
            for (int nk = 0; nk < 4; ++nk) {
#pragma unroll
                for (int r = 0; r < 4; ++r) {
                    float p = exp2f(__builtin_fmaf(st[nk][mq][r], SC, -m));
                    st[nk][mq][r] = p;
                    ls += p;
                }
            }
            ls += __shfl_xor(ls, 16);
            ls += __shfl_xor(ls, 32);
            l_s[mq] += ls;

            // P -> bf16 pairs -> per-wave LDS (b64 stores)
#pragma unroll
            for (int nk = 0; nk < 4; ++nk) {
                uint2 pk2;
                pk2.x = cvt_pk_bf16(st[nk][mq][0], st[nk][mq][1]);
                pk2.y = cvt_pk_bf16(st[nk][mq][2], st[nk][mq][3]);
                *(uint2*)&Ps[w][mq * 16 + l15][nk * 16 + lg * 4] = pk2;
            }
        }

        // ---- PV: O[q][d] += P[q][key] * V[key][d]
        __builtin_amdgcn_s_setprio(1);
#pragma unroll
        for (int kk = 0; kk < 2; ++kk) {
            s8v pf[2], vf[4];
#pragma unroll
            for (int mq = 0; mq < 2; ++mq)
                pf[mq] = *(const s8v*)&Ps[w][mq * 16 + l15][kk * 32 + lg * 8];
#pragma unroll
            for (int nd = 0; nd < 4; ++nd) {
                int swz = (2 * nd + (l15 >> 3)) & 3;
                vf[nd] = *(const s8v*)&Vt[nd * 16 + l15][(kk * 32 + lg * 8) ^ (swz << 4)];
            }
#pragma unroll
            for (int mq = 0; mq < 2; ++mq)
#pragma unroll
                for (int nd = 0; nd < 4; ++nd)
                    of[mq][nd] = mfma_bf16(pf[mq], vf[nd], of[mq][nd]);
        }
        __builtin_amdgcn_s_setprio(0);
        __syncthreads();
    }

    // epilogue: divide by softmax sum, write bf16
#pragma unroll
    for (int mq = 0; mq < 2; ++mq) {
        float rinv = 1.0f / l_s[mq];
        float iv[4];
#pragma unroll
        for (int r = 0; r < 4; ++r) iv[r] = __shfl(rinv, lg * 4 + r);
#pragma unroll
        for (int nd = 0; nd < 4; ++nd)
#pragma unroll
            for (int r = 0; r < 4; ++r) {
                int row = q0 + w * 32 + mq * 16 + lg * 4 + r;
                attn[((size_t)b * S_ + row) * DIM_ + h * HD_ + nd * 16 + l15] =
                    (short)f2b(of[mq][nd][r] * iv[r]);
            }
    }
}

// ---------------------------------------------------------------------------
extern "C" void kernel_launch(void* const* d_in, const int* in_sizes, int n_in,
                              void* d_out, int out_size, void* d_ws, size_t ws_size,
                              hipStream_t stream) {
    const float* x        = (const float*)d_in[0];
    const float* w_qkv    = (const float*)d_in[1];
    const float* b_qkv    = (const float*)d_in[2];
    const float* q_norm_w = (const float*)d_in[3];
    const float* k_norm_w = (const float*)d_in[4];
    const float* w_out    = (const float*)d_in[5];
    const float* b_out    = (const float*)d_in[6];
    float* out = (float*)d_out;

    // workspace layout (~170 MiB)
    const size_t OFF_QKV = 0;                          //  96 MiB: qkv bf16 [16384][3072]
    const size_t OFF_ATT = 100663296;                  //  32 MiB: attn bf16 [16384][1024]
    const size_t OFF_XB  = OFF_ATT + 33554432;         //  32 MiB: x bf16 [16384][1024]
    const size_t OFF_WQ  = OFF_XB + 33554432;          //   6 MiB: w_qkv^T bf16
    const size_t OFF_WO  = OFF_WQ + 6291456;           //   2 MiB: w_out^T bf16
    const size_t OFF_CT  = OFF_WO + 2097152;           // 256 KiB: cos table
    const size_t OFF_ST  = OFF_CT + 262144;            // 256 KiB: sin table
    const size_t NEED    = OFF_ST + 262144;

    if (ws_size < NEED) {
        hipMemsetAsync(d_out, 0, (size_t)out_size * sizeof(float), stream);
        return;
    }

    char* ws = (char*)d_ws;
    short* qkv   = (short*)(ws + OFF_QKV);
    short* attnb = (short*)(ws + OFF_ATT);
    short* xb    = (short*)(ws + OFF_XB);
    short* wqkvT = (short*)(ws + OFF_WQ);
    short* woutT = (short*)(ws + OFF_WO);
    float* cos_t = (float*)(ws + OFF_CT);
    float* sin_t = (float*)(ws + OFF_ST);

    // 0: tables, conversions, weight transposes
    rope_tables<<<dim3(256), dim3(256), 0, stream>>>(cos_t, sin_t);
    f32_to_bf16_vec<<<dim3(8192), dim3(256), 0, stream>>>(x, xb, 2097152);
    transpose_to_bf16<<<dim3(96, 32), dim3(256), 0, stream>>>(w_qkv, wqkvT, 1024, 3072);
    transpose_to_bf16<<<dim3(32, 32), dim3(256), 0, stream>>>(w_out, woutT, 1024, 1024);

    // 1: qkv = x @ w_qkv + b_qkv, fused RMSNorm+RoPE epilogue on q,k columns.
    gemm_glds<short, true><<<dim3(3072), dim3(256), 0, stream>>>(
        xb, wqkvT, b_qkv, qkv, 16384, 3072, 1024, 24,
        q_norm_w, k_norm_w, cos_t, sin_t);

    // 2: flash attention -> attnb (bf16)
    attn_mfma<<<dim3(8, 256), dim3(256), 0, stream>>>(qkv, attnb);

    // 3: out = attn @ w_out + b_out (fp32 out)
    gemm_glds<float, false><<<dim3(1024), dim3(256), 0, stream>>>(
        attnb, woutT, b_out, out, 16384, 1024, 1024, 8,
        nullptr, nullptr, nullptr, nullptr);
}